// Round 9
// baseline (612.307 us; speedup 1.0000x reference)
//
#include <hip/hip_runtime.h>
#include <cstdint>
#include <cstddef>
#include <math.h>

#define NNODES 30000
#define NEDGES 480000

typedef _Float16 f16x8 __attribute__((ext_vector_type(8)));
typedef float f32x4 __attribute__((ext_vector_type(4)));

constexpr unsigned ENC_NEGINF = 0x007FFFFFu;  // encode(-inf)

__device__ __forceinline__ unsigned enc_f32(float f) {
  unsigned u = __float_as_uint(f);
  return (u & 0x80000000u) ? ~u : (u | 0x80000000u);
}
__device__ __forceinline__ float dec_f32(unsigned e) {
  unsigned u = (e & 0x80000000u) ? (e ^ 0x80000000u) : ~e;
  return __uint_as_float(u);
}

__global__ void fill_u32(unsigned* __restrict__ p, int n, unsigned v) {
  int i = blockIdx.x * 256 + threadIdx.x;
  if (i < n) p[i] = v;
}

// ---- CSR build: histogram -> exclusive scan -> scatter (sorted by dst) ----
__global__ void hist_kernel(const int* __restrict__ eidx, int* __restrict__ deg) {
  int e = blockIdx.x * 256 + threadIdx.x;
  if (e < NEDGES) atomicAdd(&deg[eidx[NEDGES + e]], 1);
}

__global__ __launch_bounds__(1024) void scan_kernel(const int* __restrict__ deg,
                                                    int* __restrict__ cur) {
  __shared__ int part[1024];
  const int tid = threadIdx.x;
  constexpr int PER = 30;  // 1024*30 = 30720 >= 30000
  int loc[PER];
  int s = 0;
  const int base = tid * PER;
#pragma unroll
  for (int i = 0; i < PER; ++i) {
    int idx = base + i;
    int v = (idx < NNODES) ? deg[idx] : 0;
    loc[i] = s;
    s += v;
  }
  part[tid] = s;
  __syncthreads();
  for (int d = 1; d < 1024; d <<= 1) {
    int t = (tid >= d) ? part[tid - d] : 0;
    __syncthreads();
    part[tid] += t;
    __syncthreads();
  }
  const int excl = part[tid] - s;
#pragma unroll
  for (int i = 0; i < PER; ++i) {
    int idx = base + i;
    if (idx < NNODES) cur[idx] = excl + loc[i];
  }
}

// Pack (dst<<16)|src — both < 30000 < 65536.
__global__ void scatter_kernel(const int* __restrict__ eidx, int* __restrict__ cur,
                               unsigned* __restrict__ sedge) {
  int e = blockIdx.x * 256 + threadIdx.x;
  if (e < NEDGES) {
    int s = eidx[e], d = eidx[NEDGES + e];
    int pos = atomicAdd(&cur[d], 1);
    sedge[pos] = ((unsigned)d << 16) | (unsigned)s;
  }
}

// Weight [Kd,Nd] -> MFMA-fragment order: Bf[((ks*NTILES + tile)*64 + lane)*8 + j]
// = W[k][n], n = tile*16 + (lane&15), k = ks*32 + (lane>>4)*8 + j.
__global__ void cvt_bfrag(const float* __restrict__ W, _Float16* __restrict__ Bf,
                          int Kd, int Nd) {
  int idx = blockIdx.x * 256 + threadIdx.x;
  if (idx >= Kd * Nd) return;
  int j = idx & 7;
  int lane = (idx >> 3) & 63;
  int rest = idx >> 9;  // ks*NTILES + tile
  int ntiles = Nd >> 4;
  int ks = rest / ntiles, tile = rest % ntiles;
  int n = tile * 16 + (lane & 15);
  int k = ks * 32 + (lane >> 4) * 8 + j;
  Bf[idx] = (_Float16)W[(size_t)k * Nd + n];
}

// pq weights -> fragment order, two outputs: diff = top - bot, and bot.
// W1 is [2K, D]; fragment index over K x D.
__global__ void cvt_pqfrag(const float* __restrict__ W1, _Float16* __restrict__ Bfd,
                           _Float16* __restrict__ Bfb, int Kd, int Dd) {
  int idx = blockIdx.x * 256 + threadIdx.x;
  if (idx >= Kd * Dd) return;
  int j = idx & 7;
  int lane = (idx >> 3) & 63;
  int rest = idx >> 9;
  int ntiles = Dd >> 4;
  int ks = rest / ntiles, tile = rest % ntiles;
  int n = tile * 16 + (lane & 15);
  int k = ks * 32 + (lane >> 4) * 8 + j;
  float top = W1[(size_t)k * Dd + n];
  float bot = W1[(size_t)(Kd + k) * Dd + n];
  Bfd[idx] = (_Float16)(top - bot);
  Bfb[idx] = (_Float16)bot;
}

// Decode encoded max-agg into f16 hcat slice (hc already offset by column).
__global__ void decode_kernel(const unsigned* __restrict__ agg, _Float16* __restrict__ hc,
                              int shift, int total) {
  int i = blockIdx.x * 256 + threadIdx.x;
  if (i < total) {
    unsigned e = agg[i];
    float v = (e == ENC_NEGINF) ? 0.0f : dec_f32(e);
    int r = i >> shift;
    int c = i & ((1 << shift) - 1);
    hc[(size_t)r * 448 + c] = (_Float16)v;
  }
}

// Layer-1 P/Q (K=3, fp32 VALU — tiny): P = x@(Wt-Wb)+b1, Q = x@Wb, f16 out.
template <int K, int D>
__global__ __launch_bounds__(256) void pq_kernel(
    const float* __restrict__ X, int ldx,
    const float* __restrict__ W1, const float* __restrict__ b1,
    _Float16* __restrict__ P, _Float16* __restrict__ Q) {
  constexpr int KT = 16;
  __shared__ float xs[64][KT + 1];
  __shared__ float wt[KT][64];
  __shared__ float wb[KT][64];
  const int tid = threadIdx.x;
  const int row0 = blockIdx.x * 64;
  const int cb0 = blockIdx.y * 64;
  const int cg = tid & 15, rg = tid >> 4;
  const int c0 = cg * 4, r0 = rg * 4;
  float p[4][4] = {}, q[4][4] = {};
  for (int k0 = 0; k0 < K; k0 += KT) {
    const int kt = (K - k0 < KT) ? (K - k0) : KT;
    for (int idx = tid; idx < 64 * KT; idx += 256) {
      int k = idx & (KT - 1), r = idx >> 4;
      if (k < kt) {
        int rr = row0 + r; if (rr >= NNODES) rr = NNODES - 1;
        xs[r][k] = X[(size_t)rr * ldx + k0 + k];
      }
    }
    for (int idx = tid; idx < KT * 64; idx += 256) {
      int k = idx >> 6, c = idx & 63;
      if (k < kt) {
        wt[k][c] = W1[(size_t)(k0 + k) * D + cb0 + c];
        wb[k][c] = W1[(size_t)(K + k0 + k) * D + cb0 + c];
      }
    }
    __syncthreads();
    for (int kk = 0; kk < kt; ++kk) {
      float xv[4];
#pragma unroll
      for (int i = 0; i < 4; ++i) xv[i] = xs[r0 + i][kk];
      const float4 wtv = *(const float4*)&wt[kk][c0];
      const float4 wbv = *(const float4*)&wb[kk][c0];
      float dv[4] = {wtv.x - wbv.x, wtv.y - wbv.y, wtv.z - wbv.z, wtv.w - wbv.w};
      float bv[4] = {wbv.x, wbv.y, wbv.z, wbv.w};
#pragma unroll
      for (int i = 0; i < 4; ++i) {
#pragma unroll
        for (int j = 0; j < 4; ++j) {
          p[i][j] = fmaf(xv[i], dv[j], p[i][j]);
          q[i][j] = fmaf(xv[i], bv[j], q[i][j]);
        }
      }
    }
    __syncthreads();
  }
  float b1v[4];
#pragma unroll
  for (int j = 0; j < 4; ++j) b1v[j] = b1[cb0 + c0 + j];
#pragma unroll
  for (int i = 0; i < 4; ++i) {
    int rr = row0 + r0 + i;
    if (rr < NNODES) {
      union { _Float16 h[4]; float2 f2; } up, uq;
#pragma unroll
      for (int j = 0; j < 4; ++j) {
        up.h[j] = (_Float16)(p[i][j] + b1v[j]);
        uq.h[j] = (_Float16)q[i][j];
      }
      *(float2*)&P[(size_t)rr * D + cb0 + c0] = up.f2;
      *(float2*)&Q[(size_t)rr * D + cb0 + c0] = uq.f2;
    }
  }
}

// MFMA P/Q for layers 2/3: reads f16 hcat (ld 448, col offset koff), dual
// accumulators share A fragments; B fragments (diff & bot) direct from L2.
// Block: 64 rows x 128 cols (4 waves x 32 cols).
template <int K, int D>
__global__ __launch_bounds__(256) void pq_mfma(
    const _Float16* __restrict__ Xh, int koff,
    const _Float16* __restrict__ Bfd, const _Float16* __restrict__ Bfb,
    const float* __restrict__ b1,
    _Float16* __restrict__ P, _Float16* __restrict__ Q) {
  constexpr int SA = K + 8;
  constexpr int NSTEP = K / 32;
  constexpr int NTILES = D / 16;
  constexpr int CH = K / 8;
  __shared__ __align__(16) _Float16 As[64 * SA];
  const int tid = threadIdx.x;
  const int wave = tid >> 6, lane = tid & 63;
  const int l16 = lane & 15, quad = lane >> 4;
  const int row0 = blockIdx.x * 64;
  const int cb0 = blockIdx.y * 128;
  for (int idx = tid; idx < 64 * CH; idx += 256) {
    int r = idx / CH, cc = idx % CH;
    int rr = row0 + r; if (rr >= NNODES) rr = NNODES - 1;
    *(f16x8*)&As[r * SA + cc * 8] = *(const f16x8*)&Xh[(size_t)rr * 448 + koff + cc * 8];
  }
  __syncthreads();
  f32x4 accP[4][2] = {}, accQ[4][2] = {};
  const int tbase = cb0 / 16 + wave * 2;
#pragma unroll
  for (int ks = 0; ks < NSTEP; ++ks) {
    f16x8 af[4], bd[2], bb[2];
#pragma unroll
    for (int nt = 0; nt < 2; ++nt) {
      size_t off = (((size_t)ks * NTILES + tbase + nt) * 64 + lane) * 8;
      bd[nt] = *(const f16x8*)(Bfd + off);
      bb[nt] = *(const f16x8*)(Bfb + off);
    }
#pragma unroll
    for (int mt = 0; mt < 4; ++mt)
      af[mt] = *(const f16x8*)&As[(mt * 16 + l16) * SA + ks * 32 + quad * 8];
#pragma unroll
    for (int mt = 0; mt < 4; ++mt)
#pragma unroll
      for (int nt = 0; nt < 2; ++nt) {
        accP[mt][nt] = __builtin_amdgcn_mfma_f32_16x16x32_f16(af[mt], bd[nt], accP[mt][nt], 0, 0, 0);
        accQ[mt][nt] = __builtin_amdgcn_mfma_f32_16x16x32_f16(af[mt], bb[nt], accQ[mt][nt], 0, 0, 0);
      }
  }
#pragma unroll
  for (int nt = 0; nt < 2; ++nt) {
    int n = cb0 + wave * 32 + nt * 16 + l16;
    float bv = b1[n];
#pragma unroll
    for (int mt = 0; mt < 4; ++mt) {
#pragma unroll
      for (int r = 0; r < 4; ++r) {
        int m = row0 + mt * 16 + quad * 4 + r;
        if (m < NNODES) {
          P[(size_t)m * D + n] = (_Float16)(accP[mt][nt][r] + bv);
          Q[(size_t)m * D + n] = (_Float16)accQ[mt][nt][r];
        }
      }
    }
  }
}

// MFMA edge kernel (dst-sorted edges): t1 = relu(Ph[dst]+Qh[src]) (f16 packed)
// -> f16 LDS (gather two-pass: all loads in flight, then pack+write);
// y = t1 @ W2, B fragments direct from global; +b2; segmented max; atomics.
template <int D>
__global__ __launch_bounds__(256) void edge_mfma(
    const unsigned* __restrict__ sedge,
    const _Float16* __restrict__ P, const _Float16* __restrict__ Q,
    const _Float16* __restrict__ Bf,  // fragment-ordered f16 W2
    const float* __restrict__ b2,
    unsigned* __restrict__ agg) {
  constexpr int BE = 64;                 // edges per block
  constexpr int MT = 4;                  // M(edge)-tiles of 16
  constexpr int NT = D / 64;             // N-tiles per wave
  constexpr int NTILES = D / 16;
  constexpr int NSTEP = D / 32;          // K steps of 32
  constexpr int SA = D + 8;              // A stride in halves
  constexpr int HALVES = (D == 64) ? 1 : 2;
  constexpr int CPH = D / HALVES;        // cols per half in phase C
  constexpr int WPH = 4 / HALVES;        // waves per half
  constexpr int SL = BE * CPH / 256;     // edges per scan slice
  constexpr int ABYTES = BE * SA * 2;
  constexpr int YBYTES = CPH * (BE + 1) * 4;
  constexpr int SBYTES = (ABYTES > YBYTES) ? ABYTES : YBYTES;
  __shared__ __align__(16) char smem[SBYTES];
  __shared__ int sSrc[BE], sDst[BE];
  _Float16* Abuf = (_Float16*)smem;
  float* ybuf = (float*)smem;            // overlays A after GEMM

  const int tid = threadIdx.x;
  const int wave = tid >> 6, lane = tid & 63;
  const int l16 = lane & 15, quad = lane >> 4;
  const int ebase = blockIdx.x * BE;
  if (tid < BE) {
    unsigned pk = sedge[ebase + tid];
    sSrc[tid] = (int)(pk & 0xFFFFu);
    sDst[tid] = (int)(pk >> 16);
  }
  __syncthreads();
  // ---- Phase A: two-pass gather — all loads first, then pack+write LDS
  {
    const int e = tid >> 2, qd = tid & 3;
    const _Float16* Pr = P + (size_t)sDst[e] * D;
    const _Float16* Qr = Q + (size_t)sSrc[e] * D;
    constexpr int NTT = D / 32;
    f16x8 pv[NTT], qv[NTT];
#pragma unroll
    for (int t = 0; t < NTT; ++t) {
      int k = (qd + 4 * t) * 8;
      pv[t] = *(const f16x8*)(Pr + k);
      qv[t] = *(const f16x8*)(Qr + k);
    }
#pragma unroll
    for (int t = 0; t < NTT; ++t) {
      int k = (qd + 4 * t) * 8;
      f16x8 s = pv[t] + qv[t];
#pragma unroll
      for (int j = 0; j < 8; ++j) s[j] = (s[j] > (_Float16)0) ? s[j] : (_Float16)0;
      *(f16x8*)&Abuf[e * SA + k] = s;
    }
  }
  __syncthreads();
  // ---- Phase B: GEMM, B fragments direct from global (no barriers)
  f32x4 acc[MT][NT] = {};
  const _Float16* BfW = Bf + ((size_t)(wave * NT) * 64 + lane) * 8;
#pragma unroll
  for (int ks = 0; ks < NSTEP; ++ks) {
    f16x8 bf[NT], af[MT];
#pragma unroll
    for (int nt = 0; nt < NT; ++nt)
      bf[nt] = *(const f16x8*)(BfW + ((size_t)ks * NTILES + nt) * 64 * 8);
#pragma unroll
    for (int mt = 0; mt < MT; ++mt)
      af[mt] = *(const f16x8*)&Abuf[(mt * 16 + l16) * SA + ks * 32 + quad * 8];
#pragma unroll
    for (int mt = 0; mt < MT; ++mt)
#pragma unroll
      for (int nt = 0; nt < NT; ++nt)
        acc[mt][nt] = __builtin_amdgcn_mfma_f32_16x16x32_f16(af[mt], bf[nt], acc[mt][nt], 0, 0, 0);
  }
  // ---- Phase C: +bias, segmented max over sorted dst, atomics
  for (int h = 0; h < HALVES; ++h) {
    __syncthreads();
    if (wave / WPH == h) {
#pragma unroll
      for (int mt = 0; mt < MT; ++mt)
#pragma unroll
        for (int nt = 0; nt < NT; ++nt) {
          int ng = wave * NT * 16 + nt * 16 + l16;
          float bias = b2[ng];
          int nl = ng - h * CPH;
#pragma unroll
          for (int r = 0; r < 4; ++r)
            ybuf[nl * (BE + 1) + mt * 16 + quad * 4 + r] = acc[mt][nt][r] + bias;
        }
    }
    __syncthreads();
    {
      const int c = tid % CPH, g = tid / CPH;
      const int es = g * SL;
      float run = -INFINITY;
      int pd = sDst[es];
      for (int e = es; e < es + SL; ++e) {
        int d = sDst[e];
        if (d != pd) {
          atomicMax(&agg[(size_t)pd * D + h * CPH + c], enc_f32(run));
          run = -INFINITY;
          pd = d;
        }
        run = fmaxf(run, ybuf[c * (BE + 1) + e]);
      }
      atomicMax(&agg[(size_t)pd * D + h * CPH + c], enc_f32(run));
    }
  }
}

// LDS/barrier-free MFMA MLP GEMM: Y = act(Xh @ W + b). Block 64 rows x 128
// cols; 4 waves, each 64x32. A fragments direct from Xh (rows L1-hot),
// B fragments direct from fragment-ordered Bf (L2-hot). fp32 acc.
template <int K, int NTOT, bool RELU, bool OUTF16>
__global__ __launch_bounds__(256) void mlp_mfma(
    const _Float16* __restrict__ Xh, const _Float16* __restrict__ Bf,
    const float* __restrict__ bias, void* __restrict__ Yv) {
  constexpr int NSTEP = K / 32;
  constexpr int NTILES = NTOT / 16;
  const int tid = threadIdx.x;
  const int wave = tid >> 6, lane = tid & 63;
  const int l16 = lane & 15, quad = lane >> 4;
  const int row0 = blockIdx.x * 64;
  const int cb0 = blockIdx.y * 128;
  int rows[4];
#pragma unroll
  for (int mt = 0; mt < 4; ++mt) {
    int r = row0 + mt * 16 + l16;
    rows[mt] = (r < NNODES) ? r : (NNODES - 1);
  }
  const int tb = cb0 / 16 + wave * 2;
  f32x4 acc[4][2] = {};
#pragma unroll
  for (int ks = 0; ks < NSTEP; ++ks) {
    f16x8 af[4], bf[2];
#pragma unroll
    for (int nt = 0; nt < 2; ++nt)
      bf[nt] = *(const f16x8*)(Bf + (((size_t)ks * NTILES + tb + nt) * 64 + lane) * 8);
#pragma unroll
    for (int mt = 0; mt < 4; ++mt)
      af[mt] = *(const f16x8*)&Xh[(size_t)rows[mt] * K + ks * 32 + quad * 8];
#pragma unroll
    for (int mt = 0; mt < 4; ++mt)
#pragma unroll
      for (int nt = 0; nt < 2; ++nt)
        acc[mt][nt] = __builtin_amdgcn_mfma_f32_16x16x32_f16(af[mt], bf[nt], acc[mt][nt], 0, 0, 0);
  }
#pragma unroll
  for (int nt = 0; nt < 2; ++nt) {
    int n = cb0 + wave * 32 + nt * 16 + l16;
    float bv = bias[n];
#pragma unroll
    for (int mt = 0; mt < 4; ++mt) {
#pragma unroll
      for (int r = 0; r < 4; ++r) {
        int m = row0 + mt * 16 + quad * 4 + r;
        if (m < NNODES) {
          float v = acc[mt][nt][r] + bv;
          if (RELU) v = fmaxf(v, 0.0f);
          if (OUTF16) ((_Float16*)Yv)[(size_t)m * NTOT + n] = (_Float16)v;
          else ((float*)Yv)[(size_t)m * NTOT + n] = v;
        }
      }
    }
  }
}

// Final 256 -> 4 projection.
__global__ __launch_bounds__(256) void final_kernel(
    const float* __restrict__ X, const float* __restrict__ W,
    const float* __restrict__ b, float* __restrict__ out) {
  __shared__ float as[64][65];
  __shared__ float ws3[256][4];
  __shared__ float bs[4];
  const int tid = threadIdx.x;
  const int row0 = blockIdx.x * 64;
  for (int idx = tid; idx < 256 * 4; idx += 256) ws3[idx >> 2][idx & 3] = W[idx];
  if (tid < 4) bs[tid] = b[tid];
  const int r = tid >> 2, c = tid & 3;
  float acc = 0.0f;
  for (int k0 = 0; k0 < 256; k0 += 64) {
    __syncthreads();
    for (int idx = tid; idx < 64 * 64; idx += 256) {
      int r2 = idx >> 6, k = idx & 63;
      int rr = row0 + r2; if (rr >= NNODES) rr = NNODES - 1;
      as[r2][k] = X[(size_t)rr * 256 + k0 + k];
    }
    __syncthreads();
#pragma unroll
    for (int kk = 0; kk < 64; ++kk) acc = fmaf(as[r][kk], ws3[k0 + kk][c], acc);
  }
  int rr = row0 + r;
  if (rr < NNODES) out[(size_t)rr * 4 + c] = acc + bs[c];
}

extern "C" void kernel_launch(void* const* d_in, const int* in_sizes, int n_in,
                              void* d_out, int out_size, void* d_ws, size_t ws_size,
                              hipStream_t stream) {
  const float* x = (const float*)d_in[0];
  const int* eidx = (const int*)d_in[1];  // int32
  const float* w1a = (const float*)d_in[3];
  const float* b1a = (const float*)d_in[4];
  const float* w1b = (const float*)d_in[5];
  const float* b1b = (const float*)d_in[6];
  const float* w2a = (const float*)d_in[7];
  const float* b2a = (const float*)d_in[8];
  const float* w2b = (const float*)d_in[9];
  const float* b2b = (const float*)d_in[10];
  const float* w3a = (const float*)d_in[11];
  const float* b3a = (const float*)d_in[12];
  const float* w3b = (const float*)d_in[13];
  const float* b3b = (const float*)d_in[14];
  const float* wm1 = (const float*)d_in[15];
  const float* bm1 = (const float*)d_in[16];
  const float* wm2 = (const float*)d_in[17];
  const float* bm2 = (const float*)d_in[18];
  const float* wm3 = (const float*)d_in[19];
  const float* bm3 = (const float*)d_in[20];
  float* out = (float*)d_out;

  // Workspace layout in halves:
  // hcat_h[N*448] | Ph[N*256] | Qh[N*256] | agg[N*256 u32] | sedge[E u32]
  //   | wm1f[448*512] | w2d/w2b[64*128 ea] | w3d/w3b[128*256 ea]     (~91 MB)
  // Overlays: deg/cur on agg (CSR build, pre-agg-init); mh1h (f16 N*512) on agg;
  // mh2 (fp32 N*256) on Ph+Qh. Edge frag weights + wm2f in d_out (434 KB).
  _Float16* wsh = (_Float16*)d_ws;
  _Float16* hcat_h = wsh;
  _Float16* Ph = wsh + (size_t)NNODES * 448;
  _Float16* Qh = Ph + (size_t)NNODES * 256;
  unsigned* agg = (unsigned*)(Qh + (size_t)NNODES * 256);
  unsigned* sedge = agg + (size_t)NNODES * 256;
  _Float16* wm1f = (_Float16*)(sedge + NEDGES);
  _Float16* w2pd = wm1f + 448 * 512;
  _Float16* w2pb = w2pd + 64 * 128;
  _Float16* w3pd = w2pb + 64 * 128;
  _Float16* w3pb = w3pd + 128 * 256;
  int* deg = (int*)agg;
  int* cur = deg + NNODES;
  _Float16* mh1h = (_Float16*)agg;
  float* mh2 = (float*)Ph;
  _Float16* w1f = (_Float16*)d_out;        // 64*64   = 4096 halves
  _Float16* w2f = w1f + 4096;              // 128*128 = 16384
  _Float16* w3f = w2f + 16384;             // 256*256 = 65536
  _Float16* wm2f = w3f + 65536;            // 512*256 = 131072 -> total 434 KB

  const int ROWB64 = (NNODES + 63) / 64;     // 469
  const int EB = (NEDGES + 255) / 256;

  // ---- Build dst-sorted edge list (CSR order), reused by all 3 layers
  fill_u32<<<(NNODES + 255) / 256, 256, 0, stream>>>((unsigned*)deg, NNODES, 0u);
  hist_kernel<<<EB, 256, 0, stream>>>(eidx, deg);
  scan_kernel<<<1, 1024, 0, stream>>>(deg, cur);
  scatter_kernel<<<EB, 256, 0, stream>>>(eidx, cur, sedge);
  // ---- fragment-ordered f16 weights
  cvt_bfrag<<<(64 * 64 + 255) / 256, 256, 0, stream>>>(w1b, w1f, 64, 64);
  cvt_bfrag<<<(128 * 128 + 255) / 256, 256, 0, stream>>>(w2b, w2f, 128, 128);
  cvt_bfrag<<<(256 * 256 + 255) / 256, 256, 0, stream>>>(w3b, w3f, 256, 256);
  cvt_bfrag<<<(448 * 512 + 255) / 256, 256, 0, stream>>>(wm1, wm1f, 448, 512);
  cvt_bfrag<<<(512 * 256 + 255) / 256, 256, 0, stream>>>(wm2, wm2f, 512, 256);
  cvt_pqfrag<<<(64 * 128 + 255) / 256, 256, 0, stream>>>(w2a, w2pd, w2pb, 64, 128);
  cvt_pqfrag<<<(128 * 256 + 255) / 256, 256, 0, stream>>>(w3a, w3pd, w3pb, 128, 256);

  // ---- EdgeConv 1: C=3 -> 64
  {
    int total = NNODES * 64;
    fill_u32<<<(total + 255) / 256, 256, 0, stream>>>(agg, total, ENC_NEGINF);
    pq_kernel<3, 64><<<dim3(ROWB64, 1), 256, 0, stream>>>(x, 3, w1a, b1a, Ph, Qh);
    edge_mfma<64><<<NEDGES / 64, 256, 0, stream>>>(sedge, Ph, Qh, w1f, b1b, agg);
    decode_kernel<<<(total + 255) / 256, 256, 0, stream>>>(agg, hcat_h + 0, 6, total);
  }
  // ---- EdgeConv 2: C=64 -> 128
  {
    int total = NNODES * 128;
    fill_u32<<<(total + 255) / 256, 256, 0, stream>>>(agg, total, ENC_NEGINF);
    pq_mfma<64, 128><<<dim3(ROWB64, 1), 256, 0, stream>>>(hcat_h, 0, w2pd, w2pb, b2a, Ph, Qh);
    edge_mfma<128><<<NEDGES / 64, 256, 0, stream>>>(sedge, Ph, Qh, w2f, b2b, agg);
    decode_kernel<<<(total + 255) / 256, 256, 0, stream>>>(agg, hcat_h + 64, 7, total);
  }
  // ---- EdgeConv 3: C=128 -> 256
  {
    int total = NNODES * 256;
    fill_u32<<<(total + 255) / 256, 256, 0, stream>>>(agg, total, ENC_NEGINF);
    pq_mfma<128, 256><<<dim3(ROWB64, 2), 256, 0, stream>>>(hcat_h, 64, w3pd, w3pb, b3a, Ph, Qh);
    edge_mfma<256><<<NEDGES / 64, 256, 0, stream>>>(sedge, Ph, Qh, w3f, b3b, agg);
    decode_kernel<<<(total + 255) / 256, 256, 0, stream>>>(agg, hcat_h + 192, 8, total);
  }
  // ---- MLP head (MFMA f16, LDS-free)
  mlp_mfma<448, 512, true, true><<<dim3(ROWB64, 4), 256, 0, stream>>>(hcat_h, wm1f, bm1, mh1h);
  mlp_mfma<512, 256, true, false><<<dim3(ROWB64, 2), 256, 0, stream>>>(mh1h, wm2f, bm2, mh2);
  final_kernel<<<ROWB64, 256, 0, stream>>>(mh2, wm3, bm3, out);
}